// Round 12
// baseline (151.420 us; speedup 1.0000x reference)
//
#include <hip/hip_runtime.h>
#include <math.h>

#define B_    4
#define C_    19
#define H_    320
#define W_    320
#define HW_   (H_*W_)
#define CHW_  (C_*HW_)
#define NPIX_ (B_*HW_)
#define NEPS_ 256
#define BIGI_ (1<<20)
#define INF_  0x3fffffff
#define IGN_  255
#define REC_  20          // padded record stride (floats): 19 logits + pad

// Compile-time exact replica of the reference eps chain: e0=1e-5f, e_{k+1}=e_k*1.2f
struct EpsTab { float v[NEPS_]; };
static constexpr EpsTab make_eps() {
  EpsTab t{}; float e = 1e-5f;
  for (int k = 0; k < NEPS_; ++k) { t.v[k] = e; e = e * 1.2f; }
  return t;
}
__device__ __constant__ EpsTab EPS = make_eps();

// ---------------- reduction helper (nw full waves) ---------------------------
__device__ __forceinline__ void block_reduce_add_w(float v, float* out, int nw) {
  #pragma unroll
  for (int o = 32; o > 0; o >>= 1) v += __shfl_down(v, o);
  __shared__ float shr[8];
  int lane = threadIdx.x & 63, wid = threadIdx.x >> 6;
  if (lane == 0) shr[wid] = v;
  __syncthreads();
  if (threadIdx.x == 0) {
    float s = 0.f;
    for (int w = 0; w < nw; ++w) s += shr[w];
    atomicAdd(out, s);
  }
}

__device__ __forceinline__ int eps_bin(float kl, const float* et) {
  // #{k : e_k < kl}, log2 guess + exact correction (identical compares to ref)
  if (!(kl > 1e-5f)) return 0;
  int g = (int)((__log2f(kl) + 16.6096404f) * 3.8017840f);
  g = min(max(g, 0), NEPS_ - 1);
  while (g < NEPS_ && et[g] < kl) ++g;
  while (g > 0 && !(et[g - 1] < kl)) --g;
  return g;
}

// ---------------- K1: row distance transform + workspace init ---------------
__global__ __launch_bounds__(320) void k_rowdt(const int* __restrict__ tgt, int* __restrict__ Rt,
                                               int* __restrict__ hist, float* __restrict__ out) {
  int bid = blockIdx.x;                  // b*H_ + i
  int b = bid / H_, i = bid - b * H_;
  int j = threadIdx.x, lane = j & 63, wv = j >> 6;
  if (bid == 0) {
    if (j < 257) hist[j] = 0;
    if (j == 319) out[0] = 0.f;
  }
  bool hd = (i < H_ - 1);
  const int* trow = tgt + b * HW_ + i * W_;
  int t0 = trow[j];
  int t1 = hd ? trow[W_ + j] : t0;
  int t0r = (j < W_ - 1) ? trow[j + 1] : t0;
  bool bnd = (t0 == IGN_) || (t1 != t0) || (t0r != t0);
  int s = bnd ? 0 : BIGI_;
  int a = s - j, c = s + j;
  #pragma unroll
  for (int o = 1; o < 64; o <<= 1) {
    int v = __shfl_up(a, o);
    if (lane >= o) a = min(a, v);
    int w = __shfl_down(c, o);
    if (lane + o < 64) c = min(c, w);
  }
  __shared__ int wa[5], wc[5];
  if (lane == 63) wa[wv] = a;
  if (lane == 0)  wc[wv] = c;
  __syncthreads();
  #pragma unroll
  for (int w = 0; w < 5; ++w) {
    if (w < wv) a = min(a, wa[w]);
    if (w > wv) c = min(c, wc[w]);
  }
  Rt[(b * W_ + j) * H_ + i] = min(a + j, c - j);   // transposed store
}

// ---------------- KT: layout transpose [B][C][HW] -> XT[g][REC_] ------------
// Pure bit-copy. Coalesced reads (lane = pixel), LDS round-trip, coalesced
// writes (lane = consecutive output floats; 76 of every 80 bytes useful).
// After this, every per-pixel consumer loads ONE contiguous 80B record
// (5 float4, 16B-aligned) instead of 19 loads at 400KB stride.
__global__ __launch_bounds__(256) void k_tr(const float* __restrict__ sl, float* __restrict__ XT) {
  int tid = threadIdx.x;
  int g0 = blockIdx.x * 256;             // first global pixel (block never straddles b)
  int b = g0 / HW_, p0 = g0 - b * HW_;
  __shared__ float X[256][REC_];         // row stride 20 floats
  const float* base = sl + (size_t)b * CHW_ + p0;
  #pragma unroll
  for (int c = 0; c < C_; ++c)
    X[tid][c] = base[c * HW_ + tid];
  __syncthreads();
  float* outb = XT + (size_t)g0 * REC_;
  #pragma unroll
  for (int k = 0; k < C_; ++k) {
    int e = k * 256 + tid;               // e in [0, 4864)
    int q = e / 19, r = e - q * 19;
    outb[q * REC_ + r] = X[q][r];
  }
  outb[tid * REC_ + 19] = 0.f;           // zero the pad slot
}

// ---------------- K0: per-pixel softmax/KL from records ---------------------
// 1 pixel/thread; own + down + right records = 15 independent float4 loads in
// ONE issue batch (one latency round-trip vs ~25 small waitcnt batches on the
// strided layout -- the measured ~30us/pass floor of rounds 1-11). All
// accumulations keep the exact c-ascending __expf order of rounds 1-11
// (values are bit-copies via k_tr), preserving the absmax=0.0 invariant.
__global__ __launch_bounds__(256) void k_soft(const float* __restrict__ XT, const int* __restrict__ tgt,
                                              float2* __restrict__ LS, float* __restrict__ kl_map,
                                              int* __restrict__ hist, float* __restrict__ out) {
  int tid = threadIdx.x;
  int g = blockIdx.x * 256 + tid;
  int b = g / HW_, p = g - b * HW_;
  int i = p / W_, j = p - i * W_;
  bool hd = (i < H_ - 1), hr = (j < W_ - 1);
  __shared__ float et[NEPS_];
  __shared__ int sh[257];
  et[tid] = EPS.v[tid];
  sh[tid] = 0;
  if (tid == 0) sh[256] = 0;
  const float4 z = make_float4(0.f, 0.f, 0.f, 0.f);
  const float4* po = (const float4*)(XT + (size_t)g * REC_);
  const float4* pd = (const float4*)(XT + (size_t)(g + W_) * REC_);
  const float4* pr = (const float4*)(XT + (size_t)(g + 1) * REC_);
  float4 o0 = po[0], o1 = po[1], o2 = po[2], o3 = po[3], o4 = po[4];
  float4 d0 = hd ? pd[0] : z, d1 = hd ? pd[1] : z, d2 = hd ? pd[2] : z,
         d3 = hd ? pd[3] : z, d4 = hd ? pd[4] : z;
  float4 r0 = hr ? pr[0] : z, r1 = hr ? pr[1] : z, r2 = hr ? pr[2] : z,
         r3 = hr ? pr[3] : z, r4 = hr ? pr[4] : z;
  int t0 = tgt[g];
  float se = 0.f, E = 0.f, dD = 0.f, sB = 0.f, dR = 0.f, sR = 0.f, xt = 0.f;
#define CH(c, X, XD, XR) { float e_ = __expf(X); se += e_; E += e_ * (X); \
  dD += e_ * (XD); sB += __expf(XD); dR += e_ * (XR); sR += __expf(XR); \
  if ((c) == t0) xt = (X); }
  CH(0,  o0.x, d0.x, r0.x) CH(1,  o0.y, d0.y, r0.y) CH(2,  o0.z, d0.z, r0.z) CH(3,  o0.w, d0.w, r0.w)
  CH(4,  o1.x, d1.x, r1.x) CH(5,  o1.y, d1.y, r1.y) CH(6,  o1.z, d1.z, r1.z) CH(7,  o1.w, d1.w, r1.w)
  CH(8,  o2.x, d2.x, r2.x) CH(9,  o2.y, d2.y, r2.y) CH(10, o2.z, d2.z, r2.z) CH(11, o2.w, d2.w, r2.w)
  CH(12, o3.x, d3.x, r3.x) CH(13, o3.y, d3.y, r3.y) CH(14, o3.z, d3.z, r3.z) CH(15, o3.w, d3.w, r3.w)
  CH(16, o4.x, d4.x, r4.x) CH(17, o4.y, d4.y, r4.y) CH(18, o4.z, d4.z, r4.z)
#undef CH
  float lz = __logf(se);
  float Sv = E / se - lz;
  float nll = (t0 != IGN_) ? (lz - xt) : 0.f;
  float kl = hd ? (Sv - dD / se + __logf(sB)) : 0.f;   // kl_tb (0 at last row)
  if (hr) kl += Sv - dR / se + __logf(sR);             // + kl_lr (logf(sR) == right pixel's own lz, bitwise)
  LS[g] = make_float2(lz, Sv);
  kl_map[g] = kl;
  __syncthreads();                       // et/sh init visible
  atomicAdd(&sh[eps_bin(kl, et)], 1);
  __syncthreads();
  if (sh[tid]) atomicAdd(&hist[tid], sh[tid]);
  if (tid == 0 && sh[256]) atomicAdd(&hist[256], sh[256]);
  block_reduce_add_w(nll, out, 4);
}

// ---------------- K2: column combine + (block 0) eps selection --------------
__global__ __launch_bounds__(H_) void k_coldt(const int* __restrict__ Rt, int* __restrict__ dist,
                                              const int* __restrict__ hist, float* __restrict__ eps_sel) {
  int b = blockIdx.x / W_, j = blockIdx.x % W_, tid = threadIdx.x;
  __shared__ int lev[9][H_];
  lev[0][tid] = Rt[(b * W_ + j) * H_ + tid];
  int Ri = lev[0][tid];
  for (int l = 1; l <= 8; ++l) {
    int half = 1 << (l - 1);
    __syncthreads();
    int other = (tid + half < H_) ? lev[l - 1][tid + half] : INF_;
    lev[l][tid] = min(lev[l - 1][tid], other);
  }
  __syncthreads();
  int i0 = tid;
  auto feas = [&](int dd) -> bool {
    int lo = max(0, i0 - dd), hi = min(H_ - 1, i0 + dd);
    int len = hi - lo + 1;
    int l = 31 - __clz(len);
    int m = min(lev[l][lo], lev[l][hi - (1 << l) + 1]);
    return m <= dd;
  };
  int d;
  int hi = min(Ri, 512);                 // d <= R[i0]
  if (!feas(hi)) d = B_ + 1 + H_ + W_;   // no seed in image
  else {
    int lo = 0;
    while (lo < hi) { int mid = (lo + hi) >> 1; if (feas(mid)) hi = mid; else lo = mid + 1; }
    d = lo;
  }
  dist[(b * H_ + i0) * W_ + j] = d;
  // block 0: eps via suffix scan of hist (bins 1..256)
  if (blockIdx.x == 0) {
    __shared__ int g[256];
    __shared__ int bestk;
    if (tid < 256) g[tid] = hist[tid + 1];
    if (tid == 0) bestk = NEPS_ - 1;
    __syncthreads();
    #pragma unroll
    for (int ofs = 1; ofs < 256; ofs <<= 1) {
      int v = 0;
      if (tid < 256) v = g[tid] + ((tid + ofs < 256) ? g[tid + ofs] : 0);
      __syncthreads();
      if (tid < 256) g[tid] = v;
      __syncthreads();
    }
    if (tid < 256 && g[tid] <= 5120) atomicMin(&bestk, tid);
    __syncthreads();
    if (tid == 0) eps_sel[0] = EPS.v[bestk];
  }
}

// ---------------- helper: one directed KL value from records ----------------
__device__ __forceinline__ float kv_dir(const float* __restrict__ XT, const float2* __restrict__ LS,
                                        int gn, float4 a0, float4 a1, float4 a2, float4 a3, float4 a4,
                                        float lzc) {
  float2 ls = LS[gn];
  float lzn = ls.x;
  const float4* xn = (const float4*)(XT + (size_t)gn * REC_);
  float4 n0 = xn[0], n1 = xn[1], n2 = xn[2], n3 = xn[3], n4 = xn[4];
  float dot = 0.f;                       // single c-ascending chain (matches old CE bitwise)
  dot += __expf(n0.x - lzn) * a0.x; dot += __expf(n0.y - lzn) * a0.y;
  dot += __expf(n0.z - lzn) * a0.z; dot += __expf(n0.w - lzn) * a0.w;
  dot += __expf(n1.x - lzn) * a1.x; dot += __expf(n1.y - lzn) * a1.y;
  dot += __expf(n1.z - lzn) * a1.z; dot += __expf(n1.w - lzn) * a1.w;
  dot += __expf(n2.x - lzn) * a2.x; dot += __expf(n2.y - lzn) * a2.y;
  dot += __expf(n2.z - lzn) * a2.z; dot += __expf(n2.w - lzn) * a2.w;
  dot += __expf(n3.x - lzn) * a3.x; dot += __expf(n3.y - lzn) * a3.y;
  dot += __expf(n3.z - lzn) * a3.z; dot += __expf(n3.w - lzn) * a3.w;
  dot += __expf(n4.x - lzn) * a4.x; dot += __expf(n4.y - lzn) * a4.y;
  dot += __expf(n4.z - lzn) * a4.z;
  return ls.y - dot + lzc;
}

// ---------------- K3: mask+direction+dterm + CE from records ----------------
// mask/dir/dterm identical to R11 (validated). CE reads 9 contiguous 80B
// records (L1-resident for a 16x16 tile) + LS pairs -- same floats, same dot
// order, same R11-validated max/sum tree. No slices access, no compaction.
__global__ __launch_bounds__(256) void k_maskce(const float* __restrict__ XT, const float2* __restrict__ LS,
                                                const float* __restrict__ kl_map, const int* __restrict__ dist,
                                                const float* __restrict__ eps_sel, float* __restrict__ out) {
  const int nx9[9] = {1,-1,0,0,-1,1,-1,1,0};
  const int ny9[9] = {0,0,-1,1,1,1,-1,-1,0};
  int tid = threadIdx.x;
  int b = blockIdx.z;
  int i0 = blockIdx.y * 16, j0 = blockIdx.x * 16;
  float eps = eps_sel[0];
  __shared__ float kt[18][19];
  __shared__ int   dt_[18][19];
  for (int e = tid; e < 324; e += 256) {
    int r = e / 18, cc = e - r * 18;
    int gi = i0 - 1 + r, gj = j0 - 1 + cc;
    bool in = (gi >= 0 && gi < H_ && gj >= 0 && gj < W_);
    int gidx = (b * H_ + gi) * W_ + gj;
    kt[r][cc]  = in ? kl_map[gidx] : -1e30f;
    dt_[r][cc] = in ? dist[gidx] : 100000;
  }
  __syncthreads();
  int li = tid >> 4, lj = tid & 15;
  bool mask = false;
  #pragma unroll
  for (int dr = 0; dr < 3; ++dr)
    #pragma unroll
    for (int dc = 0; dc < 3; ++dc)
      mask |= (kt[li + dr][lj + dc] > eps);
  int best = INF_, dir = 0;
  #pragma unroll
  for (int k = 0; k < 9; ++k) {
    int r = dt_[li + 1 + nx9[k]][lj + 1 + ny9[k]];
    if (r < best) { best = r; dir = k; }
  }
  bool valid = mask && (dir != 8);
  float acc = 0.f;
  if (valid) {
    int i = i0 + li, j = j0 + lj;
    acc = fminf((float)dt_[li + 1][lj + 1], 20.f) * (1.f / 20.f);
    int label = min(dir, 7);
    int gp = b * HW_ + i * W_ + j;
    float lzc = LS[gp].x;
    const float4* xo = (const float4*)(XT + (size_t)gp * REC_);
    float4 a0 = xo[0], a1 = xo[1], a2 = xo[2], a3 = xo[3], a4 = xo[4];
    float kv0, kv1, kv2, kv3, kv4, kv5, kv6, kv7;
#define SLOTK(K, KV) { \
    int ic = i + nx9[K]; ic = ic < 0 ? 0 : (ic > H_ - 1 ? H_ - 1 : ic); \
    int jc = j + ny9[K]; jc = jc < 0 ? 0 : (jc > W_ - 1 ? W_ - 1 : jc); \
    KV = kv_dir(XT, LS, b * HW_ + ic * W_ + jc, a0, a1, a2, a3, a4, lzc); }
    SLOTK(0, kv0) SLOTK(1, kv1) SLOTK(2, kv2) SLOTK(3, kv3)
    SLOTK(4, kv4) SLOTK(5, kv5) SLOTK(6, kv6) SLOTK(7, kv7)
#undef SLOTK
    // max/sum trees: exact R11-validated pairing
    float kmax = fmaxf(fmaxf(fmaxf(kv0, kv1), fmaxf(kv2, kv3)),
                       fmaxf(fmaxf(kv4, kv5), fmaxf(kv6, kv7)));
    float s01 = __expf(kv0 - kmax) + __expf(kv1 - kmax);
    float s23 = __expf(kv2 - kmax) + __expf(kv3 - kmax);
    float s45 = __expf(kv4 - kmax) + __expf(kv5 - kmax);
    float s67 = __expf(kv6 - kmax) + __expf(kv7 - kmax);
    float ssum = (s01 + s23) + (s45 + s67);
    float kll = label == 0 ? kv0 : label == 1 ? kv1 : label == 2 ? kv2 : label == 3 ? kv3
              : label == 4 ? kv4 : label == 5 ? kv5 : label == 6 ? kv6 : kv7;
    acc += kmax + __logf(ssum) - kll;
  }
  block_reduce_add_w(acc, out, 4);
}

// ---------------- launch -----------------------------------------------------
extern "C" void kernel_launch(void* const* d_in, const int* in_sizes, int n_in,
                              void* d_out, int out_size, void* d_ws, size_t ws_size,
                              hipStream_t stream) {
  const float* sl  = (const float*)d_in[0];
  const int*   tgt = (const int*)d_in[1];
  float* out = (float*)d_out;

  int*    hist    = (int*)d_ws;                // 257 ints (zeroed by k_rowdt)
  float*  eps_sel = (float*)d_ws + 320;
  float2* LS      = (float2*)((float*)d_ws + 512);      // (logZ, S) per pixel
  float*  kl_map  = (float*)d_ws + 512 + 2 * NPIX_;
  int*    dist    = (int*)(kl_map + NPIX_);
  int*    Rt      = dist + NPIX_;
  float*  XT      = (float*)(Rt + NPIX_);      // [NPIX][REC_] records, 16B-aligned

  k_rowdt<<<B_ * H_, W_, 0, stream>>>(tgt, Rt, hist, out);
  k_tr<<<NPIX_ / 256, 256, 0, stream>>>(sl, XT);
  k_soft<<<NPIX_ / 256, 256, 0, stream>>>(XT, tgt, LS, kl_map, hist, out);
  k_coldt<<<B_ * W_, H_, 0, stream>>>(Rt, dist, hist, eps_sel);
  k_maskce<<<dim3(W_ / 16, H_ / 16, B_), 256, 0, stream>>>(XT, LS, kl_map, dist, eps_sel, out);
}

// Round 13
// 145.464 us; speedup vs baseline: 1.0409x; 1.0409x over previous
//
#include <hip/hip_runtime.h>
#include <math.h>

#define B_    4
#define C_    19
#define H_    320
#define W_    320
#define HW_   (H_*W_)
#define CHW_  (C_*HW_)
#define NPIX_ (B_*HW_)
#define NEPS_ 256
#define BIGI_ (1<<20)
#define INF_  0x3fffffff
#define IGN_  255
#define REC_  20          // padded record stride (floats)

// Compile-time exact replica of the reference eps chain: e0=1e-5f, e_{k+1}=e_k*1.2f
struct EpsTab { float v[NEPS_]; };
static constexpr EpsTab make_eps() {
  EpsTab t{}; float e = 1e-5f;
  for (int k = 0; k < NEPS_; ++k) { t.v[k] = e; e = e * 1.2f; }
  return t;
}
__device__ __constant__ EpsTab EPS = make_eps();

// ---------------- reduction helper (nw full waves) ---------------------------
__device__ __forceinline__ void block_reduce_add_w(float v, float* out, int nw) {
  #pragma unroll
  for (int o = 32; o > 0; o >>= 1) v += __shfl_down(v, o);
  __shared__ float shr[8];
  int lane = threadIdx.x & 63, wid = threadIdx.x >> 6;
  if (lane == 0) shr[wid] = v;
  __syncthreads();
  if (threadIdx.x == 0) {
    float s = 0.f;
    for (int w = 0; w < nw; ++w) s += shr[w];
    atomicAdd(out, s);
  }
}

__device__ __forceinline__ int eps_bin(float kl, const float* et) {
  // #{k : e_k < kl}, log2 guess + exact correction (identical compares to ref)
  if (!(kl > 1e-5f)) return 0;
  int g = (int)((__log2f(kl) + 16.6096404f) * 3.8017840f);
  g = min(max(g, 0), NEPS_ - 1);
  while (g < NEPS_ && et[g] < kl) ++g;
  while (g > 0 && !(et[g - 1] < kl)) --g;
  return g;
}

// ---------------- K1: row distance transform + workspace init ---------------
__global__ __launch_bounds__(320) void k_rowdt(const int* __restrict__ tgt, int* __restrict__ Rt,
                                               int* __restrict__ hist, float* __restrict__ out) {
  int bid = blockIdx.x;                  // b*H_ + i
  int b = bid / H_, i = bid - b * H_;
  int j = threadIdx.x, lane = j & 63, wv = j >> 6;
  if (bid == 0) {
    if (j < 257) hist[j] = 0;
    if (j == 319) out[0] = 0.f;
  }
  bool hd = (i < H_ - 1);
  const int* trow = tgt + b * HW_ + i * W_;
  int t0 = trow[j];
  int t1 = hd ? trow[W_ + j] : t0;
  int t0r = (j < W_ - 1) ? trow[j + 1] : t0;
  bool bnd = (t0 == IGN_) || (t1 != t0) || (t0r != t0);
  int s = bnd ? 0 : BIGI_;
  int a = s - j, c = s + j;
  #pragma unroll
  for (int o = 1; o < 64; o <<= 1) {
    int v = __shfl_up(a, o);
    if (lane >= o) a = min(a, v);
    int w = __shfl_down(c, o);
    if (lane + o < 64) c = min(c, w);
  }
  __shared__ int wa[5], wc[5];
  if (lane == 63) wa[wv] = a;
  if (lane == 0)  wc[wv] = c;
  __syncthreads();
  #pragma unroll
  for (int w = 0; w < 5; ++w) {
    if (w < wv) a = min(a, wa[w]);
    if (w > wv) c = min(c, wc[w]);
  }
  Rt[(b * W_ + j) * H_ + i] = min(a + j, c - j);   // transposed store
}

// ---------------- K0: per-PAIR softmax/KL (f2b) + X/P record stores ---------
// EXACT R6 f2b load/compute structure (measured best ~30us; all original
// accumulations bitwise-unchanged). Added: stash own logits (registers) and,
// after lz is known, store two contiguous 80B records per pixel:
//   X[g][c] = x[c]                  (bit-copy)
//   P[g][c] = __expf(x[c] - lz)     (same expf input bits as R6-maskce's CE)
// Fire-and-forget stores, ZERO added loads (the R11 mistake avoided).
// k_maskce's CE then needs no slices access and no exps at all.
__global__ __launch_bounds__(256) void k_soft(const float* __restrict__ sl, const int* __restrict__ tgt,
                                              float2* __restrict__ LS, float* __restrict__ kl_map,
                                              float* __restrict__ X, float* __restrict__ P,
                                              int* __restrict__ hist, float* __restrict__ out) {
  int t = blockIdx.x * 256 + threadIdx.x;        // pair index, 0..NPIX_/2-1
  int b = t / (HW_ / 2), q = t - b * (HW_ / 2);
  int p = q * 2;                                 // pixel base (j even)
  int i = p / W_, j = p - i * W_;
  bool hd = (i < H_ - 1);
  bool hr1 = (j + 2 < W_);                       // pixel1 has a right neighbor
  __shared__ float et[NEPS_];
  __shared__ int sh[257];
  et[threadIdx.x] = EPS.v[threadIdx.x];
  sh[threadIdx.x] = 0;
  if (threadIdx.x == 0) sh[256] = 0;

  const float* base = sl + (size_t)b * CHW_ + p;
  int2 t2 = *(const int2*)(tgt + b * HW_ + p);

  float x0s[C_], x1s[C_];                        // own logits stash (static idx)
  float se0=0.f,se1=0.f, E0=0.f,E1=0.f;
  float dD0=0.f,dD1=0.f, sB0=0.f,sB1=0.f;
  float dR0=0.f,dR1=0.f, sR1=0.f;
  float xt0=0.f,xt1=0.f;
  #pragma unroll
  for (int c0 = 0; c0 < C_; c0 += 5) {
    const int NB = (c0 + 5 <= C_) ? 5 : (C_ - c0);
    float2 xo[5], xd[5];
    float  xr[5];
    #pragma unroll
    for (int k = 0; k < NB; ++k) {
      const float* pc = base + (c0 + k) * HW_;
      xo[k] = *(const float2*)pc;
      xd[k] = hd ? *(const float2*)(pc + W_) : make_float2(0.f, 0.f);
      xr[k] = hr1 ? pc[2] : 0.f;
    }
    #pragma unroll
    for (int k = 0; k < NB; ++k) {
      int c = c0 + k;
      x0s[c] = xo[k].x; x1s[c] = xo[k].y;
      float e0 = __expf(xo[k].x), e1 = __expf(xo[k].y);
      se0 += e0; E0 += e0 * xo[k].x;
      se1 += e1; E1 += e1 * xo[k].y;
      dD0 += e0 * xd[k].x; dD1 += e1 * xd[k].y;
      sB0 += __expf(xd[k].x); sB1 += __expf(xd[k].y);
      dR0 += e0 * xo[k].y; dR1 += e1 * xr[k];
      sR1 += __expf(xr[k]);
      if (c == t2.x) xt0 = xo[k].x;
      if (c == t2.y) xt1 = xo[k].y;
    }
  }
  float lz0 = __logf(se0), lz1 = __logf(se1);
  float Sv0 = E0 / se0 - lz0, Sv1 = E1 / se1 - lz1;
  float nll = ((t2.x != IGN_) ? (lz0 - xt0) : 0.f) + ((t2.y != IGN_) ? (lz1 - xt1) : 0.f);
  float kl0 = hd ? (Sv0 - dD0 / se0 + __logf(sB0)) : 0.f;
  float kl1 = hd ? (Sv1 - dD1 / se1 + __logf(sB1)) : 0.f;
  kl0 += Sv0 - dR0 / se0 + lz1;
  if (hr1) kl1 += Sv1 - dR1 / se1 + __logf(sR1);

  // ---- record stores (fire-and-forget; no added loads) ----
  int gp = b * HW_ + p;
  {
    float4* Xp0 = (float4*)(X + (size_t)gp * REC_);
    Xp0[0] = make_float4(x0s[0], x0s[1], x0s[2], x0s[3]);
    Xp0[1] = make_float4(x0s[4], x0s[5], x0s[6], x0s[7]);
    Xp0[2] = make_float4(x0s[8], x0s[9], x0s[10], x0s[11]);
    Xp0[3] = make_float4(x0s[12], x0s[13], x0s[14], x0s[15]);
    Xp0[4] = make_float4(x0s[16], x0s[17], x0s[18], 0.f);
    float4* Xp1 = (float4*)(X + (size_t)(gp + 1) * REC_);
    Xp1[0] = make_float4(x1s[0], x1s[1], x1s[2], x1s[3]);
    Xp1[1] = make_float4(x1s[4], x1s[5], x1s[6], x1s[7]);
    Xp1[2] = make_float4(x1s[8], x1s[9], x1s[10], x1s[11]);
    Xp1[3] = make_float4(x1s[12], x1s[13], x1s[14], x1s[15]);
    Xp1[4] = make_float4(x1s[16], x1s[17], x1s[18], 0.f);
    float p0s[C_], p1s[C_];
    #pragma unroll
    for (int c = 0; c < C_; ++c) {
      p0s[c] = __expf(x0s[c] - lz0);     // same expf input bits as R6-maskce CE
      p1s[c] = __expf(x1s[c] - lz1);
    }
    float4* Pp0 = (float4*)(P + (size_t)gp * REC_);
    Pp0[0] = make_float4(p0s[0], p0s[1], p0s[2], p0s[3]);
    Pp0[1] = make_float4(p0s[4], p0s[5], p0s[6], p0s[7]);
    Pp0[2] = make_float4(p0s[8], p0s[9], p0s[10], p0s[11]);
    Pp0[3] = make_float4(p0s[12], p0s[13], p0s[14], p0s[15]);
    Pp0[4] = make_float4(p0s[16], p0s[17], p0s[18], 0.f);
    float4* Pp1 = (float4*)(P + (size_t)(gp + 1) * REC_);
    Pp1[0] = make_float4(p1s[0], p1s[1], p1s[2], p1s[3]);
    Pp1[1] = make_float4(p1s[4], p1s[5], p1s[6], p1s[7]);
    Pp1[2] = make_float4(p1s[8], p1s[9], p1s[10], p1s[11]);
    Pp1[3] = make_float4(p1s[12], p1s[13], p1s[14], p1s[15]);
    Pp1[4] = make_float4(p1s[16], p1s[17], p1s[18], 0.f);
  }
  LS[gp]     = make_float2(lz0, Sv0);
  LS[gp + 1] = make_float2(lz1, Sv1);
  *(float2*)(kl_map + gp) = make_float2(kl0, kl1);
  __syncthreads();                       // et/sh init visible
  atomicAdd(&sh[eps_bin(kl0, et)], 1);
  atomicAdd(&sh[eps_bin(kl1, et)], 1);
  __syncthreads();
  if (sh[threadIdx.x]) atomicAdd(&hist[threadIdx.x], sh[threadIdx.x]);
  if (threadIdx.x == 0 && sh[256]) atomicAdd(&hist[256], sh[256]);
  block_reduce_add_w(nll, out, 4);
}

// ---------------- K2: column combine + (block 0) eps selection --------------
__global__ __launch_bounds__(H_) void k_coldt(const int* __restrict__ Rt, int* __restrict__ dist,
                                              const int* __restrict__ hist, float* __restrict__ eps_sel) {
  int b = blockIdx.x / W_, j = blockIdx.x % W_, tid = threadIdx.x;
  __shared__ int lev[9][H_];
  lev[0][tid] = Rt[(b * W_ + j) * H_ + tid];
  int Ri = lev[0][tid];
  for (int l = 1; l <= 8; ++l) {
    int half = 1 << (l - 1);
    __syncthreads();
    int other = (tid + half < H_) ? lev[l - 1][tid + half] : INF_;
    lev[l][tid] = min(lev[l - 1][tid], other);
  }
  __syncthreads();
  int i0 = tid;
  auto feas = [&](int dd) -> bool {
    int lo = max(0, i0 - dd), hi = min(H_ - 1, i0 + dd);
    int len = hi - lo + 1;
    int l = 31 - __clz(len);
    int m = min(lev[l][lo], lev[l][hi - (1 << l) + 1]);
    return m <= dd;
  };
  int d;
  int hi = min(Ri, 512);                 // d <= R[i0]
  if (!feas(hi)) d = B_ + 1 + H_ + W_;   // no seed in image
  else {
    int lo = 0;
    while (lo < hi) { int mid = (lo + hi) >> 1; if (feas(mid)) hi = mid; else lo = mid + 1; }
    d = lo;
  }
  dist[(b * H_ + i0) * W_ + j] = d;
  // block 0: eps via suffix scan of hist (bins 1..256)
  if (blockIdx.x == 0) {
    __shared__ int g[256];
    __shared__ int bestk;
    if (tid < 256) g[tid] = hist[tid + 1];
    if (tid == 0) bestk = NEPS_ - 1;
    __syncthreads();
    #pragma unroll
    for (int ofs = 1; ofs < 256; ofs <<= 1) {
      int v = 0;
      if (tid < 256) v = g[tid] + ((tid + ofs < 256) ? g[tid + ofs] : 0);
      __syncthreads();
      if (tid < 256) g[tid] = v;
      __syncthreads();
    }
    if (tid < 256 && g[tid] <= 5120) atomicMin(&bestk, tid);
    __syncthreads();
    if (tid == 0) eps_sel[0] = EPS.v[bestk];
  }
}

// ---------------- K3: mask+direction+dterm + CE from X/P records ------------
// mask/dir/dterm identical to R6/R11 (validated). CE per valid pixel: own X
// record + 8 neighbor P records + LS pairs -- 45 independent float4 loads,
// one batch, L1-resident within a tile. dot = sum_c P_n[c]*X_p[c] in the same
// c-ascending order as R6's CE (P_n holds the SAME expf result bits); kv =
// Sn - dot + lzc; R11-validated max/sum tree. No slices, no exps, no
// compaction.
__global__ __launch_bounds__(256) void k_maskce(const float* __restrict__ X, const float* __restrict__ P,
                                                const float2* __restrict__ LS, const float* __restrict__ kl_map,
                                                const int* __restrict__ dist, const float* __restrict__ eps_sel,
                                                float* __restrict__ out) {
  const int nx9[9] = {1,-1,0,0,-1,1,-1,1,0};
  const int ny9[9] = {0,0,-1,1,1,1,-1,-1,0};
  int tid = threadIdx.x;
  int b = blockIdx.z;
  int i0 = blockIdx.y * 16, j0 = blockIdx.x * 16;
  float eps = eps_sel[0];
  __shared__ float kt[18][19];
  __shared__ int   dt_[18][19];
  for (int e = tid; e < 324; e += 256) {
    int r = e / 18, cc = e - r * 18;
    int gi = i0 - 1 + r, gj = j0 - 1 + cc;
    bool in = (gi >= 0 && gi < H_ && gj >= 0 && gj < W_);
    int gidx = (b * H_ + gi) * W_ + gj;
    kt[r][cc]  = in ? kl_map[gidx] : -1e30f;
    dt_[r][cc] = in ? dist[gidx] : 100000;
  }
  __syncthreads();
  int li = tid >> 4, lj = tid & 15;
  bool mask = false;
  #pragma unroll
  for (int dr = 0; dr < 3; ++dr)
    #pragma unroll
    for (int dc = 0; dc < 3; ++dc)
      mask |= (kt[li + dr][lj + dc] > eps);
  int best = INF_, dir = 0;
  #pragma unroll
  for (int k = 0; k < 9; ++k) {
    int r = dt_[li + 1 + nx9[k]][lj + 1 + ny9[k]];
    if (r < best) { best = r; dir = k; }
  }
  bool valid = mask && (dir != 8);
  float acc = 0.f;
  if (valid) {
    int i = i0 + li, j = j0 + lj;
    acc = fminf((float)dt_[li + 1][lj + 1], 20.f) * (1.f / 20.f);
    int label = min(dir, 7);
    int gp = b * HW_ + i * W_ + j;
    float lzc = LS[gp].x;
    const float4* xo = (const float4*)(X + (size_t)gp * REC_);
    float4 a0 = xo[0], a1 = xo[1], a2 = xo[2], a3 = xo[3], a4 = xo[4];
    float kv0, kv1, kv2, kv3, kv4, kv5, kv6, kv7;
#define SLOTK(K, KV) { \
    int ic = i + nx9[K]; ic = ic < 0 ? 0 : (ic > H_ - 1 ? H_ - 1 : ic); \
    int jc = j + ny9[K]; jc = jc < 0 ? 0 : (jc > W_ - 1 ? W_ - 1 : jc); \
    int gn = b * HW_ + ic * W_ + jc; \
    float2 lsn = LS[gn]; \
    const float4* pn = (const float4*)(P + (size_t)gn * REC_); \
    float4 p0 = pn[0], p1 = pn[1], p2 = pn[2], p3 = pn[3], p4 = pn[4]; \
    float dot = 0.f; \
    dot += p0.x * a0.x; dot += p0.y * a0.y; dot += p0.z * a0.z; dot += p0.w * a0.w; \
    dot += p1.x * a1.x; dot += p1.y * a1.y; dot += p1.z * a1.z; dot += p1.w * a1.w; \
    dot += p2.x * a2.x; dot += p2.y * a2.y; dot += p2.z * a2.z; dot += p2.w * a2.w; \
    dot += p3.x * a3.x; dot += p3.y * a3.y; dot += p3.z * a3.z; dot += p3.w * a3.w; \
    dot += p4.x * a4.x; dot += p4.y * a4.y; dot += p4.z * a4.z; \
    KV = lsn.y - dot + lzc; }
    SLOTK(0, kv0) SLOTK(1, kv1) SLOTK(2, kv2) SLOTK(3, kv3)
    SLOTK(4, kv4) SLOTK(5, kv5) SLOTK(6, kv6) SLOTK(7, kv7)
#undef SLOTK
    // max/sum trees: exact R11-validated pairing
    float kmax = fmaxf(fmaxf(fmaxf(kv0, kv1), fmaxf(kv2, kv3)),
                       fmaxf(fmaxf(kv4, kv5), fmaxf(kv6, kv7)));
    float s01 = __expf(kv0 - kmax) + __expf(kv1 - kmax);
    float s23 = __expf(kv2 - kmax) + __expf(kv3 - kmax);
    float s45 = __expf(kv4 - kmax) + __expf(kv5 - kmax);
    float s67 = __expf(kv6 - kmax) + __expf(kv7 - kmax);
    float ssum = (s01 + s23) + (s45 + s67);
    float kll = label == 0 ? kv0 : label == 1 ? kv1 : label == 2 ? kv2 : label == 3 ? kv3
              : label == 4 ? kv4 : label == 5 ? kv5 : label == 6 ? kv6 : kv7;
    acc += kmax + __logf(ssum) - kll;
  }
  block_reduce_add_w(acc, out, 4);
}

// ---------------- launch -----------------------------------------------------
extern "C" void kernel_launch(void* const* d_in, const int* in_sizes, int n_in,
                              void* d_out, int out_size, void* d_ws, size_t ws_size,
                              hipStream_t stream) {
  const float* sl  = (const float*)d_in[0];
  const int*   tgt = (const int*)d_in[1];
  float* out = (float*)d_out;

  int*    hist    = (int*)d_ws;                // 257 ints (zeroed by k_rowdt)
  float*  eps_sel = (float*)d_ws + 320;
  float2* LS      = (float2*)((float*)d_ws + 512);      // (logZ, S) per pixel
  float*  kl_map  = (float*)d_ws + 512 + 2 * NPIX_;
  int*    dist    = (int*)(kl_map + NPIX_);
  int*    Rt      = dist + NPIX_;
  float*  X       = (float*)(Rt + NPIX_);      // [NPIX][REC_] logits records
  float*  P       = X + (size_t)NPIX_ * REC_;  // [NPIX][REC_] softmax records

  k_rowdt<<<B_ * H_, W_, 0, stream>>>(tgt, Rt, hist, out);
  k_soft<<<NPIX_ / 2 / 256, 256, 0, stream>>>(sl, tgt, LS, kl_map, X, P, hist, out);
  k_coldt<<<B_ * W_, H_, 0, stream>>>(Rt, dist, hist, eps_sel);
  k_maskce<<<dim3(W_ / 16, H_ / 16, B_), 256, 0, stream>>>(X, P, LS, kl_map, dist, eps_sel, out);
}

// Round 14
// 134.146 us; speedup vs baseline: 1.1288x; 1.0844x over previous
//
#include <hip/hip_runtime.h>
#include <math.h>

#define B_    4
#define C_    19
#define H_    320
#define W_    320
#define HW_   (H_*W_)
#define CHW_  (C_*HW_)
#define NPIX_ (B_*HW_)
#define NEPS_ 256
#define BIGI_ (1<<20)
#define INF_  0x3fffffff
#define IGN_  255
#define REC_  20          // padded record stride (floats)

// Compile-time exact replica of the reference eps chain: e0=1e-5f, e_{k+1}=e_k*1.2f
struct EpsTab { float v[NEPS_]; };
static constexpr EpsTab make_eps() {
  EpsTab t{}; float e = 1e-5f;
  for (int k = 0; k < NEPS_; ++k) { t.v[k] = e; e = e * 1.2f; }
  return t;
}
__device__ __constant__ EpsTab EPS = make_eps();

// ---------------- reduction helper (nw full waves) ---------------------------
__device__ __forceinline__ void block_reduce_add_w(float v, float* out, int nw) {
  #pragma unroll
  for (int o = 32; o > 0; o >>= 1) v += __shfl_down(v, o);
  __shared__ float shr[8];
  int lane = threadIdx.x & 63, wid = threadIdx.x >> 6;
  if (lane == 0) shr[wid] = v;
  __syncthreads();
  if (threadIdx.x == 0) {
    float s = 0.f;
    for (int w = 0; w < nw; ++w) s += shr[w];
    atomicAdd(out, s);
  }
}

__device__ __forceinline__ int eps_bin(float kl, const float* et) {
  // #{k : e_k < kl}, log2 guess + exact correction (identical compares to ref)
  if (!(kl > 1e-5f)) return 0;
  int g = (int)((__log2f(kl) + 16.6096404f) * 3.8017840f);
  g = min(max(g, 0), NEPS_ - 1);
  while (g < NEPS_ && et[g] < kl) ++g;
  while (g > 0 && !(et[g - 1] < kl)) --g;
  return g;
}

// ---------------- K1: row distance transform + workspace init ---------------
__global__ __launch_bounds__(320) void k_rowdt(const int* __restrict__ tgt, int* __restrict__ Rt,
                                               int* __restrict__ hist, float* __restrict__ out) {
  int bid = blockIdx.x;                  // b*H_ + i
  int b = bid / H_, i = bid - b * H_;
  int j = threadIdx.x, lane = j & 63, wv = j >> 6;
  if (bid == 0) {
    if (j < 257) hist[j] = 0;
    if (j == 319) out[0] = 0.f;
  }
  bool hd = (i < H_ - 1);
  const int* trow = tgt + b * HW_ + i * W_;
  int t0 = trow[j];
  int t1 = hd ? trow[W_ + j] : t0;
  int t0r = (j < W_ - 1) ? trow[j + 1] : t0;
  bool bnd = (t0 == IGN_) || (t1 != t0) || (t0r != t0);
  int s = bnd ? 0 : BIGI_;
  int a = s - j, c = s + j;
  #pragma unroll
  for (int o = 1; o < 64; o <<= 1) {
    int v = __shfl_up(a, o);
    if (lane >= o) a = min(a, v);
    int w = __shfl_down(c, o);
    if (lane + o < 64) c = min(c, w);
  }
  __shared__ int wa[5], wc[5];
  if (lane == 63) wa[wv] = a;
  if (lane == 0)  wc[wv] = c;
  __syncthreads();
  #pragma unroll
  for (int w = 0; w < 5; ++w) {
    if (w < wv) a = min(a, wa[w]);
    if (w > wv) c = min(c, wc[w]);
  }
  Rt[(b * W_ + j) * H_ + i] = min(a + j, c - j);   // transposed store
}

// ---------------- K0: per-PAIR softmax/KL (f2b) + LDS-coalesced X/P stores --
// R13 structure with the record stores routed through LDS: thread's 40-float
// record pair goes to RS[256][41] (pad-41 -> conflict-free lane writes), then
// the block cooperatively stores its 40KB region with linear float4s
// (rec*40+e0 == f4*4). Fixes R13's measured write-path inefficiency (stride-
// 160 stores = 64 transactions/instr, 2.28 TB/s effective). P values are
// computed straight into LDS (__expf(x-lz), same input bits as R13 -> same
// output bits; absmax 0.0 invariant). No added global loads.
__global__ __launch_bounds__(256) void k_soft(const float* __restrict__ sl, const int* __restrict__ tgt,
                                              float2* __restrict__ LS, float* __restrict__ kl_map,
                                              float* __restrict__ X, float* __restrict__ P,
                                              int* __restrict__ hist, float* __restrict__ out) {
  int tid = threadIdx.x;
  int t = blockIdx.x * 256 + tid;                // pair index, 0..NPIX_/2-1
  int b = t / (HW_ / 2), q = t - b * (HW_ / 2);
  int p = q * 2;                                 // pixel base (j even)
  int i = p / W_, j = p - i * W_;
  bool hd = (i < H_ - 1);
  bool hr1 = (j + 2 < W_);                       // pixel1 has a right neighbor
  __shared__ float et[NEPS_];
  __shared__ int sh[257];
  __shared__ float RS[256][41];                  // record staging (X, then P)
  et[tid] = EPS.v[tid];
  sh[tid] = 0;
  if (tid == 0) sh[256] = 0;

  const float* base = sl + (size_t)b * CHW_ + p;
  int2 t2 = *(const int2*)(tgt + b * HW_ + p);

  float x0s[C_], x1s[C_];                        // own logits stash (static idx)
  float se0=0.f,se1=0.f, E0=0.f,E1=0.f;
  float dD0=0.f,dD1=0.f, sB0=0.f,sB1=0.f;
  float dR0=0.f,dR1=0.f, sR1=0.f;
  float xt0=0.f,xt1=0.f;
  #pragma unroll
  for (int c0 = 0; c0 < C_; c0 += 5) {
    const int NB = (c0 + 5 <= C_) ? 5 : (C_ - c0);
    float2 xo[5], xd[5];
    float  xr[5];
    #pragma unroll
    for (int k = 0; k < NB; ++k) {
      const float* pc = base + (c0 + k) * HW_;
      xo[k] = *(const float2*)pc;
      xd[k] = hd ? *(const float2*)(pc + W_) : make_float2(0.f, 0.f);
      xr[k] = hr1 ? pc[2] : 0.f;
    }
    #pragma unroll
    for (int k = 0; k < NB; ++k) {
      int c = c0 + k;
      x0s[c] = xo[k].x; x1s[c] = xo[k].y;
      float e0 = __expf(xo[k].x), e1 = __expf(xo[k].y);
      se0 += e0; E0 += e0 * xo[k].x;
      se1 += e1; E1 += e1 * xo[k].y;
      dD0 += e0 * xd[k].x; dD1 += e1 * xd[k].y;
      sB0 += __expf(xd[k].x); sB1 += __expf(xd[k].y);
      dR0 += e0 * xo[k].y; dR1 += e1 * xr[k];
      sR1 += __expf(xr[k]);
      if (c == t2.x) xt0 = xo[k].x;
      if (c == t2.y) xt1 = xo[k].y;
    }
  }
  float lz0 = __logf(se0), lz1 = __logf(se1);
  float Sv0 = E0 / se0 - lz0, Sv1 = E1 / se1 - lz1;
  float nll = ((t2.x != IGN_) ? (lz0 - xt0) : 0.f) + ((t2.y != IGN_) ? (lz1 - xt1) : 0.f);
  float kl0 = hd ? (Sv0 - dD0 / se0 + __logf(sB0)) : 0.f;
  float kl1 = hd ? (Sv1 - dD1 / se1 + __logf(sB1)) : 0.f;
  kl0 += Sv0 - dR0 / se0 + lz1;
  if (hr1) kl1 += Sv1 - dR1 / se1 + __logf(sR1);

  // ---- X records via LDS coalescing ----
  #pragma unroll
  for (int c = 0; c < C_; ++c) { RS[tid][c] = x0s[c]; RS[tid][20 + c] = x1s[c]; }
  RS[tid][19] = 0.f; RS[tid][40] = 0.f;          // hmm: pad slots are [19] and [39]
  RS[tid][39] = 0.f;
  __syncthreads();
  {
    float* xb = X + (size_t)blockIdx.x * (256 * 2 * REC_);
    #pragma unroll
    for (int r = 0; r < 10; ++r) {
      int f4 = r * 256 + tid;                    // 0..2559
      int rec = f4 / 10, e0 = (f4 - rec * 10) * 4;
      float4 v = make_float4(RS[rec][e0], RS[rec][e0 + 1], RS[rec][e0 + 2], RS[rec][e0 + 3]);
      *(float4*)(xb + (size_t)f4 * 4) = v;       // rec*40+e0 == f4*4: linear, coalesced
    }
  }
  __syncthreads();
  // ---- P records via LDS coalescing (exp computed straight into LDS) ----
  #pragma unroll
  for (int c = 0; c < C_; ++c) {
    RS[tid][c]      = __expf(x0s[c] - lz0);      // same input bits as R13 -> same output
    RS[tid][20 + c] = __expf(x1s[c] - lz1);
  }
  RS[tid][19] = 0.f; RS[tid][39] = 0.f;
  __syncthreads();
  {
    float* pb = P + (size_t)blockIdx.x * (256 * 2 * REC_);
    #pragma unroll
    for (int r = 0; r < 10; ++r) {
      int f4 = r * 256 + tid;
      int rec = f4 / 10, e0 = (f4 - rec * 10) * 4;
      float4 v = make_float4(RS[rec][e0], RS[rec][e0 + 1], RS[rec][e0 + 2], RS[rec][e0 + 3]);
      *(float4*)(pb + (size_t)f4 * 4) = v;
    }
  }

  int gp = b * HW_ + p;
  LS[gp]     = make_float2(lz0, Sv0);
  LS[gp + 1] = make_float2(lz1, Sv1);
  *(float2*)(kl_map + gp) = make_float2(kl0, kl1);
  __syncthreads();                       // et/sh init + staging done
  atomicAdd(&sh[eps_bin(kl0, et)], 1);
  atomicAdd(&sh[eps_bin(kl1, et)], 1);
  __syncthreads();
  if (sh[tid]) atomicAdd(&hist[tid], sh[tid]);
  if (tid == 0 && sh[256]) atomicAdd(&hist[256], sh[256]);
  block_reduce_add_w(nll, out, 4);
}

// ---------------- K2: column combine + (block 0) eps selection --------------
__global__ __launch_bounds__(H_) void k_coldt(const int* __restrict__ Rt, int* __restrict__ dist,
                                              const int* __restrict__ hist, float* __restrict__ eps_sel) {
  int b = blockIdx.x / W_, j = blockIdx.x % W_, tid = threadIdx.x;
  __shared__ int lev[9][H_];
  lev[0][tid] = Rt[(b * W_ + j) * H_ + tid];
  int Ri = lev[0][tid];
  for (int l = 1; l <= 8; ++l) {
    int half = 1 << (l - 1);
    __syncthreads();
    int other = (tid + half < H_) ? lev[l - 1][tid + half] : INF_;
    lev[l][tid] = min(lev[l - 1][tid], other);
  }
  __syncthreads();
  int i0 = tid;
  auto feas = [&](int dd) -> bool {
    int lo = max(0, i0 - dd), hi = min(H_ - 1, i0 + dd);
    int len = hi - lo + 1;
    int l = 31 - __clz(len);
    int m = min(lev[l][lo], lev[l][hi - (1 << l) + 1]);
    return m <= dd;
  };
  int d;
  int hi = min(Ri, 512);                 // d <= R[i0]
  if (!feas(hi)) d = B_ + 1 + H_ + W_;   // no seed in image
  else {
    int lo = 0;
    while (lo < hi) { int mid = (lo + hi) >> 1; if (feas(mid)) hi = mid; else lo = mid + 1; }
    d = lo;
  }
  dist[(b * H_ + i0) * W_ + j] = d;
  // block 0: eps via suffix scan of hist (bins 1..256)
  if (blockIdx.x == 0) {
    __shared__ int g[256];
    __shared__ int bestk;
    if (tid < 256) g[tid] = hist[tid + 1];
    if (tid == 0) bestk = NEPS_ - 1;
    __syncthreads();
    #pragma unroll
    for (int ofs = 1; ofs < 256; ofs <<= 1) {
      int v = 0;
      if (tid < 256) v = g[tid] + ((tid + ofs < 256) ? g[tid + ofs] : 0);
      __syncthreads();
      if (tid < 256) g[tid] = v;
      __syncthreads();
    }
    if (tid < 256 && g[tid] <= 5120) atomicMin(&bestk, tid);
    __syncthreads();
    if (tid == 0) eps_sel[0] = EPS.v[bestk];
  }
}

// ---------------- K3: mask+direction+dterm + CE from X/P records ------------
// EXACT R13 version (validated absmax 0.0, ~13us by budget algebra).
__global__ __launch_bounds__(256) void k_maskce(const float* __restrict__ X, const float* __restrict__ P,
                                                const float2* __restrict__ LS, const float* __restrict__ kl_map,
                                                const int* __restrict__ dist, const float* __restrict__ eps_sel,
                                                float* __restrict__ out) {
  const int nx9[9] = {1,-1,0,0,-1,1,-1,1,0};
  const int ny9[9] = {0,0,-1,1,1,1,-1,-1,0};
  int tid = threadIdx.x;
  int b = blockIdx.z;
  int i0 = blockIdx.y * 16, j0 = blockIdx.x * 16;
  float eps = eps_sel[0];
  __shared__ float kt[18][19];
  __shared__ int   dt_[18][19];
  for (int e = tid; e < 324; e += 256) {
    int r = e / 18, cc = e - r * 18;
    int gi = i0 - 1 + r, gj = j0 - 1 + cc;
    bool in = (gi >= 0 && gi < H_ && gj >= 0 && gj < W_);
    int gidx = (b * H_ + gi) * W_ + gj;
    kt[r][cc]  = in ? kl_map[gidx] : -1e30f;
    dt_[r][cc] = in ? dist[gidx] : 100000;
  }
  __syncthreads();
  int li = tid >> 4, lj = tid & 15;
  bool mask = false;
  #pragma unroll
  for (int dr = 0; dr < 3; ++dr)
    #pragma unroll
    for (int dc = 0; dc < 3; ++dc)
      mask |= (kt[li + dr][lj + dc] > eps);
  int best = INF_, dir = 0;
  #pragma unroll
  for (int k = 0; k < 9; ++k) {
    int r = dt_[li + 1 + nx9[k]][lj + 1 + ny9[k]];
    if (r < best) { best = r; dir = k; }
  }
  bool valid = mask && (dir != 8);
  float acc = 0.f;
  if (valid) {
    int i = i0 + li, j = j0 + lj;
    acc = fminf((float)dt_[li + 1][lj + 1], 20.f) * (1.f / 20.f);
    int label = min(dir, 7);
    int gp = b * HW_ + i * W_ + j;
    float lzc = LS[gp].x;
    const float4* xo = (const float4*)(X + (size_t)gp * REC_);
    float4 a0 = xo[0], a1 = xo[1], a2 = xo[2], a3 = xo[3], a4 = xo[4];
    float kv0, kv1, kv2, kv3, kv4, kv5, kv6, kv7;
#define SLOTK(K, KV) { \
    int ic = i + nx9[K]; ic = ic < 0 ? 0 : (ic > H_ - 1 ? H_ - 1 : ic); \
    int jc = j + ny9[K]; jc = jc < 0 ? 0 : (jc > W_ - 1 ? W_ - 1 : jc); \
    int gn = b * HW_ + ic * W_ + jc; \
    float2 lsn = LS[gn]; \
    const float4* pn = (const float4*)(P + (size_t)gn * REC_); \
    float4 p0 = pn[0], p1 = pn[1], p2 = pn[2], p3 = pn[3], p4 = pn[4]; \
    float dot = 0.f; \
    dot += p0.x * a0.x; dot += p0.y * a0.y; dot += p0.z * a0.z; dot += p0.w * a0.w; \
    dot += p1.x * a1.x; dot += p1.y * a1.y; dot += p1.z * a1.z; dot += p1.w * a1.w; \
    dot += p2.x * a2.x; dot += p2.y * a2.y; dot += p2.z * a2.z; dot += p2.w * a2.w; \
    dot += p3.x * a3.x; dot += p3.y * a3.y; dot += p3.z * a3.z; dot += p3.w * a3.w; \
    dot += p4.x * a4.x; dot += p4.y * a4.y; dot += p4.z * a4.z; \
    KV = lsn.y - dot + lzc; }
    SLOTK(0, kv0) SLOTK(1, kv1) SLOTK(2, kv2) SLOTK(3, kv3)
    SLOTK(4, kv4) SLOTK(5, kv5) SLOTK(6, kv6) SLOTK(7, kv7)
#undef SLOTK
    // max/sum trees: exact R11/R13-validated pairing
    float kmax = fmaxf(fmaxf(fmaxf(kv0, kv1), fmaxf(kv2, kv3)),
                       fmaxf(fmaxf(kv4, kv5), fmaxf(kv6, kv7)));
    float s01 = __expf(kv0 - kmax) + __expf(kv1 - kmax);
    float s23 = __expf(kv2 - kmax) + __expf(kv3 - kmax);
    float s45 = __expf(kv4 - kmax) + __expf(kv5 - kmax);
    float s67 = __expf(kv6 - kmax) + __expf(kv7 - kmax);
    float ssum = (s01 + s23) + (s45 + s67);
    float kll = label == 0 ? kv0 : label == 1 ? kv1 : label == 2 ? kv2 : label == 3 ? kv3
              : label == 4 ? kv4 : label == 5 ? kv5 : label == 6 ? kv6 : kv7;
    acc += kmax + __logf(ssum) - kll;
  }
  block_reduce_add_w(acc, out, 4);
}

// ---------------- launch -----------------------------------------------------
extern "C" void kernel_launch(void* const* d_in, const int* in_sizes, int n_in,
                              void* d_out, int out_size, void* d_ws, size_t ws_size,
                              hipStream_t stream) {
  const float* sl  = (const float*)d_in[0];
  const int*   tgt = (const int*)d_in[1];
  float* out = (float*)d_out;

  int*    hist    = (int*)d_ws;                // 257 ints (zeroed by k_rowdt)
  float*  eps_sel = (float*)d_ws + 320;
  float2* LS      = (float2*)((float*)d_ws + 512);      // (logZ, S) per pixel
  float*  kl_map  = (float*)d_ws + 512 + 2 * NPIX_;
  int*    dist    = (int*)(kl_map + NPIX_);
  int*    Rt      = dist + NPIX_;
  float*  X       = (float*)(Rt + NPIX_);      // [NPIX][REC_] logits records
  float*  P       = X + (size_t)NPIX_ * REC_;  // [NPIX][REC_] softmax records

  k_rowdt<<<B_ * H_, W_, 0, stream>>>(tgt, Rt, hist, out);
  k_soft<<<NPIX_ / 2 / 256, 256, 0, stream>>>(sl, tgt, LS, kl_map, X, P, hist, out);
  k_coldt<<<B_ * W_, H_, 0, stream>>>(Rt, dist, hist, eps_sel);
  k_maskce<<<dim3(W_ / 16, H_ / 16, B_), 256, 0, stream>>>(X, P, LS, kl_map, dist, eps_sel, out);
}